// Round 2
// baseline (1278.087 us; speedup 1.0000x reference)
//
#include <hip/hip_runtime.h>

// Accumulator layout in d_ws: NCOPY copies (one per XCD), each SoA with
// NACC arrays of n_frag floats:
//  0: count
//  1..3: sum f (x,y,z)
//  4..6: sum torque (x,y,z)
//  7..12: sum r r^T upper triangle: xx, yy, zz, xy, xz, yz
#define NACC 13
#define NXCD 8

__device__ __forceinline__ int xcc_id() {
    int x;
    // HW_REG_XCC_ID = 20 on gfx94x/gfx950; numeric form for assembler safety.
    asm volatile("s_getreg_b32 %0, hwreg(20, 0, 32)" : "=s"(x));
    return x & (NXCD - 1);
}

template <int SCOPE, bool MULTI>
__global__ void atom_accum_kernel(const float* __restrict__ f_atom,
                                  const float* __restrict__ atom_pos,
                                  const float* __restrict__ T_frag,
                                  const int*   __restrict__ frag_id,
                                  float* __restrict__ acc,
                                  int n_atom, int n_frag) {
    int i = blockIdx.x * blockDim.x + threadIdx.x;
    if (i >= n_atom) return;

    float* a = acc;
    if (MULTI) {
        int copy = xcc_id();
        a += (size_t)copy * NACC * n_frag;
    }

    float fx = f_atom[3 * i + 0];
    float fy = f_atom[3 * i + 1];
    float fz = f_atom[3 * i + 2];
    float px = atom_pos[3 * i + 0];
    float py = atom_pos[3 * i + 1];
    float pz = atom_pos[3 * i + 2];
    int fid = frag_id[i];

    float rx = px - T_frag[3 * fid + 0];
    float ry = py - T_frag[3 * fid + 1];
    float rz = pz - T_frag[3 * fid + 2];

    // torque = r x f
    float tx = ry * fz - rz * fy;
    float ty = rz * fx - rx * fz;
    float tz = rx * fy - ry * fx;

#define ACC(c, v) __hip_atomic_fetch_add(&a[(c) * n_frag + fid], (v), __ATOMIC_RELAXED, SCOPE)
    ACC(0, 1.0f);
    ACC(1, fx);
    ACC(2, fy);
    ACC(3, fz);
    ACC(4, tx);
    ACC(5, ty);
    ACC(6, tz);
    ACC(7, rx * rx);
    ACC(8, ry * ry);
    ACC(9, rz * rz);
    ACC(10, rx * ry);
    ACC(11, rx * rz);
    ACC(12, ry * rz);
#undef ACC
}

template <bool MULTI>
__global__ void finalize_kernel(const float* __restrict__ acc,
                                const int* __restrict__ frag_sizes,
                                float* __restrict__ out,
                                int n_frag) {
    int i = blockIdx.x * blockDim.x + threadIdx.x;
    if (i >= n_frag) return;

    float s[NACC];
#pragma unroll
    for (int c = 0; c < NACC; ++c) s[c] = 0.0f;

    int ncopy = MULTI ? NXCD : 1;
    for (int x = 0; x < ncopy; ++x) {
        const float* a = acc + (size_t)x * NACC * n_frag;
#pragma unroll
        for (int c = 0; c < NACC; ++c) s[c] += a[(size_t)c * n_frag + i];
    }

    float cnt = s[0];
    float sfx = s[1], sfy = s[2], sfz = s[3];
    float ttx = s[4], tty = s[5], ttz = s[6];
    double sxx = (double)s[7], syy = (double)s[8], szz = (double)s[9];
    double sxy = (double)s[10], sxz = (double)s[11], syz = (double)s[12];

    // v = sum_f / max(count, 1)
    float inv_cnt = 1.0f / fmaxf(cnt, 1.0f);
    out[3 * i + 0] = sfx * inv_cnt;
    out[3 * i + 1] = sfy * inv_cnt;
    out[3 * i + 2] = sfz * inv_cnt;

    // I = (sxx+syy+szz) * eye - S + eps*eye   (S = sum r r^T)
    const double eps = 1e-4;
    double d = sxx + syy + szz;
    double a00 = d - sxx + eps;
    double a11 = d - syy + eps;
    double a22 = d - szz + eps;
    double a01 = -sxy;
    double a02 = -sxz;
    double a12 = -syz;

    // Cramer's rule (symmetric 3x3), in double for stability near eps-scale
    // eigenvalues on single-atom fragments.
    double c00 = a11 * a22 - a12 * a12;
    double c01 = a02 * a12 - a01 * a22;
    double c02 = a01 * a12 - a02 * a11;
    double det = a00 * c00 + a01 * c01 + a02 * c02;
    double inv_det = (det != 0.0) ? 1.0 / det : 0.0;

    double c11 = a00 * a22 - a02 * a02;
    double c12 = a01 * a02 - a00 * a12;
    double c22 = a00 * a11 - a01 * a01;

    double tx = (double)ttx, ty = (double)tty, tz = (double)ttz;
    double ox = (c00 * tx + c01 * ty + c02 * tz) * inv_det;
    double oy = (c01 * tx + c11 * ty + c12 * tz) * inv_det;
    double oz = (c02 * tx + c12 * ty + c22 * tz) * inv_det;

    int fs = frag_sizes[i];
    float* om = out + 3 * (size_t)n_frag;
    if (fs <= 1) {
        om[3 * i + 0] = 0.0f;
        om[3 * i + 1] = 0.0f;
        om[3 * i + 2] = 0.0f;
    } else {
        om[3 * i + 0] = (float)ox;
        om[3 * i + 1] = (float)oy;
        om[3 * i + 2] = (float)oz;
    }
}

extern "C" void kernel_launch(void* const* d_in, const int* in_sizes, int n_in,
                              void* d_out, int out_size, void* d_ws, size_t ws_size,
                              hipStream_t stream) {
    const float* f_atom   = (const float*)d_in[0];
    const float* atom_pos = (const float*)d_in[1];
    const float* T_frag   = (const float*)d_in[2];
    const int*   frag_id  = (const int*)d_in[3];
    // d_in[4] is the n_frag scalar on device; derive on host from T_frag size.
    const int*   frag_sizes = (const int*)d_in[5];

    int n_atom = in_sizes[0] / 3;
    int n_frag = in_sizes[2] / 3;

    size_t copy_bytes = (size_t)NACC * n_frag * sizeof(float);
    bool multi = (ws_size >= copy_bytes * NXCD);

    float* acc = (float*)d_ws;
    size_t acc_bytes = multi ? copy_bytes * NXCD : copy_bytes;
    hipMemsetAsync(acc, 0, acc_bytes, stream);

    int threads = 256;
    int blocks_a = (n_atom + threads - 1) / threads;
    int blocks_f = (n_frag + threads - 1) / threads;

    if (multi) {
        // XCD-local accumulation: each XCD's workgroups atomically update only
        // their own copy (indexed by the hardware XCC_ID register), so
        // workgroup-scope atomics (which stay in the local L2) are sufficient.
        // The end-of-kernel release fence writes back L2 before finalize reads.
        atom_accum_kernel<__HIP_MEMORY_SCOPE_WORKGROUP, true>
            <<<blocks_a, threads, 0, stream>>>(f_atom, atom_pos, T_frag,
                                               frag_id, acc, n_atom, n_frag);
        finalize_kernel<true><<<blocks_f, threads, 0, stream>>>(acc, frag_sizes,
                                                                (float*)d_out, n_frag);
    } else {
        atom_accum_kernel<__HIP_MEMORY_SCOPE_AGENT, false>
            <<<blocks_a, threads, 0, stream>>>(f_atom, atom_pos, T_frag,
                                               frag_id, acc, n_atom, n_frag);
        finalize_kernel<false><<<blocks_f, threads, 0, stream>>>(acc, frag_sizes,
                                                                 (float*)d_out, n_frag);
    }
}

// Round 3
// 253.899 us; speedup vs baseline: 5.0338x; 5.0338x over previous
//
#include <hip/hip_runtime.h>

// ---------------------------------------------------------------------------
// Strategy: bucketed counting-sort + LDS segmented reduction.
//   Buckets of 512 consecutive fragment ids (NB = ceil(n_frag/512) <= 512).
//   K1 hist:    per-block LDS histogram of fid>>9 -> global cnt[NB]
//   K2 scan:    single-block exclusive scan -> start[NB], cursor[NB]
//   K3 scatter: per block: LDS hist of its chunk, one atomicAdd per
//               (block,bucket) to reserve a range, LDS rank per atom,
//               write 32B payload (f, r, fid) to its slot.
//   K4 reduce:  one block per bucket: LDS acc[512][13] via ds atomics,
//               then per-fragment 3x3 double Cramer solve -> out.
// Fallback (ws too small): direct device-scope atomic accumulation (round-1).
// ---------------------------------------------------------------------------

#define BSHIFT 9
#define BFRAGS (1 << BSHIFT)   // 512 fragments per bucket
#define NBMAX  512
#define NACC   13

// ---------------- fallback path (round-1, known correct) -------------------
__global__ void atom_accum_kernel(const float* __restrict__ f_atom,
                                  const float* __restrict__ atom_pos,
                                  const float* __restrict__ T_frag,
                                  const int*   __restrict__ frag_id,
                                  float* __restrict__ acc,
                                  int n_atom, int n_frag) {
    int i = blockIdx.x * blockDim.x + threadIdx.x;
    if (i >= n_atom) return;
    float fx = f_atom[3 * i + 0], fy = f_atom[3 * i + 1], fz = f_atom[3 * i + 2];
    float px = atom_pos[3 * i + 0], py = atom_pos[3 * i + 1], pz = atom_pos[3 * i + 2];
    int fid = frag_id[i];
    float rx = px - T_frag[3 * fid + 0];
    float ry = py - T_frag[3 * fid + 1];
    float rz = pz - T_frag[3 * fid + 2];
    atomicAdd(&acc[0 * n_frag + fid], 1.0f);
    atomicAdd(&acc[1 * n_frag + fid], fx);
    atomicAdd(&acc[2 * n_frag + fid], fy);
    atomicAdd(&acc[3 * n_frag + fid], fz);
    atomicAdd(&acc[4 * n_frag + fid], ry * fz - rz * fy);
    atomicAdd(&acc[5 * n_frag + fid], rz * fx - rx * fz);
    atomicAdd(&acc[6 * n_frag + fid], rx * fy - ry * fx);
    atomicAdd(&acc[7 * n_frag + fid], rx * rx);
    atomicAdd(&acc[8 * n_frag + fid], ry * ry);
    atomicAdd(&acc[9 * n_frag + fid], rz * rz);
    atomicAdd(&acc[10 * n_frag + fid], rx * ry);
    atomicAdd(&acc[11 * n_frag + fid], rx * rz);
    atomicAdd(&acc[12 * n_frag + fid], ry * rz);
}

// Shared finalize math (per fragment), in double for stability.
__device__ __forceinline__ void solve_frag(const float s[NACC], int fs,
                                           float* vout, float* oout) {
    float inv_cnt = 1.0f / fmaxf(s[0], 1.0f);
    vout[0] = s[1] * inv_cnt;
    vout[1] = s[2] * inv_cnt;
    vout[2] = s[3] * inv_cnt;

    double sxx = (double)s[7], syy = (double)s[8], szz = (double)s[9];
    double sxy = (double)s[10], sxz = (double)s[11], syz = (double)s[12];
    const double eps = 1e-4;
    double d = sxx + syy + szz;
    double a00 = d - sxx + eps, a11 = d - syy + eps, a22 = d - szz + eps;
    double a01 = -sxy, a02 = -sxz, a12 = -syz;

    double c00 = a11 * a22 - a12 * a12;
    double c01 = a02 * a12 - a01 * a22;
    double c02 = a01 * a12 - a02 * a11;
    double det = a00 * c00 + a01 * c01 + a02 * c02;
    double inv_det = (det != 0.0) ? 1.0 / det : 0.0;
    double c11 = a00 * a22 - a02 * a02;
    double c12 = a01 * a02 - a00 * a12;
    double c22 = a00 * a11 - a01 * a01;

    double tx = (double)s[4], ty = (double)s[5], tz = (double)s[6];
    if (fs <= 1) {
        oout[0] = 0.0f; oout[1] = 0.0f; oout[2] = 0.0f;
    } else {
        oout[0] = (float)((c00 * tx + c01 * ty + c02 * tz) * inv_det);
        oout[1] = (float)((c01 * tx + c11 * ty + c12 * tz) * inv_det);
        oout[2] = (float)((c02 * tx + c12 * ty + c22 * tz) * inv_det);
    }
}

__global__ void finalize_accum_kernel(const float* __restrict__ acc,
                                      const int* __restrict__ frag_sizes,
                                      float* __restrict__ out, int n_frag) {
    int i = blockIdx.x * blockDim.x + threadIdx.x;
    if (i >= n_frag) return;
    float s[NACC];
#pragma unroll
    for (int c = 0; c < NACC; ++c) s[c] = acc[(size_t)c * n_frag + i];
    float v[3], o[3];
    solve_frag(s, frag_sizes[i], v, o);
    out[3 * i + 0] = v[0]; out[3 * i + 1] = v[1]; out[3 * i + 2] = v[2];
    float* om = out + 3 * (size_t)n_frag;
    om[3 * i + 0] = o[0]; om[3 * i + 1] = o[1]; om[3 * i + 2] = o[2];
}

// ---------------- sort-based path ------------------------------------------

__global__ void hist_kernel(const int* __restrict__ frag_id,
                            unsigned* __restrict__ cnt, int n_atom, int nb) {
    __shared__ unsigned h[NBMAX];
    for (int t = threadIdx.x; t < NBMAX; t += blockDim.x) h[t] = 0;
    __syncthreads();
    int stride = gridDim.x * blockDim.x;
    for (int i = blockIdx.x * blockDim.x + threadIdx.x; i < n_atom; i += stride)
        atomicAdd(&h[frag_id[i] >> BSHIFT], 1u);
    __syncthreads();
    for (int t = threadIdx.x; t < nb; t += blockDim.x)
        if (h[t]) atomicAdd(&cnt[t], h[t]);
}

__global__ void scan_kernel(const unsigned* __restrict__ cnt,
                            unsigned* __restrict__ start,
                            unsigned* __restrict__ cursor, int nb) {
    __shared__ unsigned s[NBMAX];
    int t = threadIdx.x;
    unsigned v = (t < nb) ? cnt[t] : 0u;
    s[t] = v;
    __syncthreads();
    for (int off = 1; off < NBMAX; off <<= 1) {
        unsigned x = (t >= off) ? s[t - off] : 0u;
        __syncthreads();
        s[t] += x;
        __syncthreads();
    }
    if (t < nb) {
        unsigned st = s[t] - v;  // exclusive
        start[t] = st;
        cursor[t] = st;
    }
}

#define SC_CHUNK 8192
#define SC_THREADS 256

__global__ void scatter_kernel(const float* __restrict__ f_atom,
                               const float* __restrict__ atom_pos,
                               const float* __restrict__ T_frag,
                               const int* __restrict__ frag_id,
                               unsigned* __restrict__ cursor,
                               float* __restrict__ payload,
                               int n_atom, int nb) {
    __shared__ unsigned h[NBMAX];
    __shared__ unsigned base[NBMAX];
    int c0 = blockIdx.x * SC_CHUNK;

    for (int t = threadIdx.x; t < NBMAX; t += SC_THREADS) h[t] = 0;
    __syncthreads();
    for (int k = 0; k < SC_CHUNK; k += SC_THREADS) {
        int i = c0 + k + threadIdx.x;
        if (i < n_atom) atomicAdd(&h[frag_id[i] >> BSHIFT], 1u);
    }
    __syncthreads();
    for (int t = threadIdx.x; t < nb; t += SC_THREADS) {
        unsigned c = h[t];
        base[t] = c ? atomicAdd(&cursor[t], c) : 0u;
    }
    __syncthreads();
    for (int t = threadIdx.x; t < NBMAX; t += SC_THREADS) h[t] = 0;
    __syncthreads();

    for (int k = 0; k < SC_CHUNK; k += SC_THREADS) {
        int i = c0 + k + threadIdx.x;
        if (i >= n_atom) continue;
        int fid = frag_id[i];
        int b = fid >> BSHIFT;
        unsigned r = atomicAdd(&h[b], 1u);      // LDS rank
        unsigned slot = base[b] + r;
        float fx = f_atom[3 * i + 0], fy = f_atom[3 * i + 1], fz = f_atom[3 * i + 2];
        float rx = atom_pos[3 * i + 0] - T_frag[3 * fid + 0];
        float ry = atom_pos[3 * i + 1] - T_frag[3 * fid + 1];
        float rz = atom_pos[3 * i + 2] - T_frag[3 * fid + 2];
        float4* p = (float4*)(payload + (size_t)slot * 8);
        p[0] = make_float4(fx, fy, fz, __int_as_float(fid));
        p[1] = make_float4(rx, ry, rz, 0.0f);
    }
}

__global__ void reduce_kernel(const float* __restrict__ payload,
                              const unsigned* __restrict__ cnt,
                              const unsigned* __restrict__ start,
                              const int* __restrict__ frag_sizes,
                              float* __restrict__ out, int n_frag) {
    __shared__ float acc[BFRAGS * NACC];   // 512*13*4 = 26624 B
    int b = blockIdx.x;
    for (int t = threadIdx.x; t < BFRAGS * NACC; t += blockDim.x) acc[t] = 0.0f;
    __syncthreads();

    unsigned n = cnt[b], s0 = start[b];
    for (unsigned t = threadIdx.x; t < n; t += blockDim.x) {
        const float4* p = (const float4*)(payload + (size_t)(s0 + t) * 8);
        float4 a = p[0];
        float4 c = p[1];
        float fx = a.x, fy = a.y, fz = a.z;
        int fid = __float_as_int(a.w);
        float rx = c.x, ry = c.y, rz = c.z;
        int lf = fid - (b << BSHIFT);
        float* A = &acc[lf * NACC];
        atomicAdd(&A[0], 1.0f);
        atomicAdd(&A[1], fx);
        atomicAdd(&A[2], fy);
        atomicAdd(&A[3], fz);
        atomicAdd(&A[4], ry * fz - rz * fy);
        atomicAdd(&A[5], rz * fx - rx * fz);
        atomicAdd(&A[6], rx * fy - ry * fx);
        atomicAdd(&A[7], rx * rx);
        atomicAdd(&A[8], ry * ry);
        atomicAdd(&A[9], rz * rz);
        atomicAdd(&A[10], rx * ry);
        atomicAdd(&A[11], rx * rz);
        atomicAdd(&A[12], ry * rz);
    }
    __syncthreads();

    int fid0 = b << BSHIFT;
    for (int lf = threadIdx.x; lf < BFRAGS; lf += blockDim.x) {
        int fid = fid0 + lf;
        if (fid >= n_frag) continue;
        float s[NACC];
#pragma unroll
        for (int c = 0; c < NACC; ++c) s[c] = acc[lf * NACC + c];
        float v[3], o[3];
        solve_frag(s, frag_sizes[fid], v, o);
        out[3 * fid + 0] = v[0]; out[3 * fid + 1] = v[1]; out[3 * fid + 2] = v[2];
        float* om = out + 3 * (size_t)n_frag;
        om[3 * fid + 0] = o[0]; om[3 * fid + 1] = o[1]; om[3 * fid + 2] = o[2];
    }
}

// ---------------------------------------------------------------------------

extern "C" void kernel_launch(void* const* d_in, const int* in_sizes, int n_in,
                              void* d_out, int out_size, void* d_ws, size_t ws_size,
                              hipStream_t stream) {
    const float* f_atom   = (const float*)d_in[0];
    const float* atom_pos = (const float*)d_in[1];
    const float* T_frag   = (const float*)d_in[2];
    const int*   frag_id  = (const int*)d_in[3];
    const int*   frag_sizes = (const int*)d_in[5];

    int n_atom = in_sizes[0] / 3;
    int n_frag = in_sizes[2] / 3;
    int nb = (n_frag + BFRAGS - 1) >> BSHIFT;

    // ws layout (sorted path): cnt[512] | start[512] | cursor[512] | pad | payload
    size_t ctrl_bytes = 8192;
    size_t payload_bytes = (size_t)n_atom * 8 * sizeof(float);
    bool sorted_ok = (nb <= NBMAX) && (ws_size >= ctrl_bytes + payload_bytes);

    if (sorted_ok) {
        unsigned* cnt    = (unsigned*)d_ws;
        unsigned* start  = cnt + NBMAX;
        unsigned* cursor = start + NBMAX;
        float* payload   = (float*)((char*)d_ws + ctrl_bytes);

        hipMemsetAsync(cnt, 0, NBMAX * sizeof(unsigned), stream);

        hist_kernel<<<256, 256, 0, stream>>>(frag_id, cnt, n_atom, nb);
        scan_kernel<<<1, NBMAX, 0, stream>>>(cnt, start, cursor, nb);
        int sc_blocks = (n_atom + SC_CHUNK - 1) / SC_CHUNK;
        scatter_kernel<<<sc_blocks, SC_THREADS, 0, stream>>>(
            f_atom, atom_pos, T_frag, frag_id, cursor, payload, n_atom, nb);
        reduce_kernel<<<nb, 256, 0, stream>>>(payload, cnt, start, frag_sizes,
                                              (float*)d_out, n_frag);
    } else {
        // fallback: direct device-scope atomic accumulation
        float* acc = (float*)d_ws;
        hipMemsetAsync(acc, 0, (size_t)NACC * n_frag * sizeof(float), stream);
        int threads = 256;
        atom_accum_kernel<<<(n_atom + threads - 1) / threads, threads, 0, stream>>>(
            f_atom, atom_pos, T_frag, frag_id, acc, n_atom, n_frag);
        finalize_accum_kernel<<<(n_frag + threads - 1) / threads, threads, 0, stream>>>(
            acc, frag_sizes, (float*)d_out, n_frag);
    }
}